// Round 1
// baseline (837.813 us; speedup 1.0000x reference)
//
#include <hip/hip_runtime.h>

typedef __bf16 bf16_t;
typedef __attribute__((ext_vector_type(8))) __bf16 bf16x8;
typedef __attribute__((ext_vector_type(4))) float f32x4;

static constexpr int Lc = 2, NEc = 4, Hc = 768, FFc = 3072, NHc = 12, HDc = 64;
static constexpr int Bc = 8, Sc = 256, Tc = 2048;

// ---------------------------------------------------------------- route
__global__ __launch_bounds__(256) void route_k(const int* __restrict__ ntp,
                                               int* __restrict__ perm,
                                               int* __restrict__ offs) {
  __shared__ int cnt[NEc];
  __shared__ int base[NEc];
  int tid = threadIdx.x;
  if (tid < NEc) cnt[tid] = 0;
  __syncthreads();
  for (int t = tid; t < Tc; t += 256) atomicAdd(&cnt[ntp[t]], 1);
  __syncthreads();
  if (tid == 0) {
    int a = 0;
    for (int e = 0; e < NEc; ++e) { base[e] = a; offs[e] = a; a += cnt[e]; }
    offs[NEc] = a;
  }
  __syncthreads();
  for (int t = tid; t < Tc; t += 256) {
    int e = ntp[t];
    int p = atomicAdd(&base[e], 1);
    perm[p] = t;
  }
}

// ---------------------------------------------------------------- PE add
__global__ __launch_bounds__(256) void pe_add(const float* __restrict__ xin,
                                              float* __restrict__ x0) {
  int p = blockIdx.x * 256 + threadIdx.x;      // pair index, 0..T*H/2-1
  int t = p / 384;
  int jj = p - t * 384;
  int s = t & 255;
  float ang = (float)s * __expf((float)jj * -0.0239852613894f); // -2*ln(1e4)/768
  float sn, cs;
  sincosf(ang, &sn, &cs);
  float2 xv = ((const float2*)xin)[p];
  float2 o;  o.x = xv.x + sn;  o.y = xv.y + cs;
  ((float2*)x0)[p] = o;
}

// ---------------------------------------------------------------- LayerNorm (1 wave / token)
__global__ __launch_bounds__(256) void ln_k(const float* __restrict__ x,
                                            const float* __restrict__ g,
                                            const float* __restrict__ bb,
                                            bf16_t* __restrict__ out) {
  int w = threadIdx.x >> 6, lane = threadIdx.x & 63;
  int t = blockIdx.x * 4 + w;
  const float4* xr = (const float4*)(x + (size_t)t * Hc);
  float4 v[3];
  float s = 0.f, s2 = 0.f;
  for (int i = 0; i < 3; ++i) {
    v[i] = xr[lane + i * 64];
    s  += v[i].x + v[i].y + v[i].z + v[i].w;
    s2 += v[i].x * v[i].x + v[i].y * v[i].y + v[i].z * v[i].z + v[i].w * v[i].w;
  }
  for (int o = 1; o < 64; o <<= 1) { s += __shfl_xor(s, o); s2 += __shfl_xor(s2, o); }
  float mu = s * (1.f / 768.f);
  float r = rsqrtf(s2 * (1.f / 768.f) - mu * mu + 1e-5f);
  bf16_t* orow = out + (size_t)t * Hc;
  for (int i = 0; i < 3; ++i) {
    int i4 = lane + i * 64;
    float4 gg = ((const float4*)g)[i4];
    float4 b4 = ((const float4*)bb)[i4];
    union { bf16_t h[4]; uint2 u; } pk;
    pk.h[0] = (bf16_t)((v[i].x - mu) * r * gg.x + b4.x);
    pk.h[1] = (bf16_t)((v[i].y - mu) * r * gg.y + b4.y);
    pk.h[2] = (bf16_t)((v[i].z - mu) * r * gg.z + b4.z);
    pk.h[3] = (bf16_t)((v[i].w - mu) * r * gg.w + b4.w);
    ((uint2*)orow)[i4] = pk.u;
  }
}

// ---------------------------------------------------------------- transpose+convert fp32 [K,N] -> bf16 [N,K]
__global__ __launch_bounds__(256) void tconv(const float* __restrict__ s0,
                                             const float* __restrict__ s1,
                                             const float* __restrict__ s2,
                                             long sstride,
                                             bf16_t* __restrict__ dst, long dstride,
                                             int K, int N) {
  int z = blockIdx.z;
  const float* src = (sstride == 0) ? (z == 0 ? s0 : (z == 1 ? s1 : s2)) : (s0 + (size_t)z * sstride);
  bf16_t* d = dst + (size_t)z * dstride;
  int n0 = blockIdx.x * 64, k0 = blockIdx.y * 64;
  __shared__ float tl[64][65];
  int c = threadIdx.x & 63, r0 = threadIdx.x >> 6;
  for (int i = 0; i < 16; ++i) {
    int r = r0 + i * 4;
    tl[r][c] = src[(size_t)(k0 + r) * N + n0 + c];
  }
  __syncthreads();
  for (int i = 0; i < 16; ++i) {
    int r = r0 + i * 4;
    d[(size_t)(n0 + r) * K + k0 + c] = (bf16_t)tl[c][r];
  }
}

// ---------------------------------------------------------------- GEMM  C[M,N] = A[M,K](bf16) * Bt[N,K]^T(bf16)
// MODE 0: QKV  (out bf16, bias by column range q|k|v)
// MODE 1: FFN1 routed (gather A rows via perm, GELU epilogue, grouped bf16 out)
// MODE 2: FFN2 routed (A grouped rows, scatter add x0 -> outF fp32)
template <int BM, int BN, int MODE>
__global__ __launch_bounds__(256) void gemm_bt(
    const bf16_t* __restrict__ A, const bf16_t* __restrict__ Bt,
    int Mtot, int K, int N, long btStride, long biasStride,
    const int* __restrict__ perm, const int* __restrict__ offs,
    const float* __restrict__ biasA, const float* __restrict__ biasB,
    const float* __restrict__ biasC,
    const float* __restrict__ xin, float* __restrict__ outF,
    bf16_t* __restrict__ outB) {
  constexpr int WM = BM / 2, WN = BN / 2, TM = WM / 16, TN = WN / 16;
  constexpr int ACH = BM * 4 / 256, BCH = BN * 4 / 256;
  __shared__ bf16_t Ald[BM * 32];
  __shared__ bf16_t Bld[BN * 32];
  int tid = threadIdx.x;
  int e = blockIdx.z;
  int m0 = blockIdx.y * BM, n0 = blockIdx.x * BN;
  int off = 0, cnt = Mtot;
  if (MODE != 0) {
    off = offs[e];
    cnt = offs[e + 1] - off;
    if (m0 >= cnt) return;
  }
  const bf16_t* B0 = Bt + (size_t)e * btStride;
  int lane = tid & 63, w = tid >> 6;
  int quad = lane >> 4, col = lane & 15;
  int wr = (w >> 1) * WM, wc = (w & 1) * WN;

  // staging descriptors
  int lr[ACH], apc[ACH], arow[ACH];
  bool avld[ACH];
  for (int c = 0; c < ACH; ++c) {
    int chunk = tid + c * 256;
    int r = chunk >> 2, pc = chunk & 3;
    int gm = m0 + r;
    bool v = gm < cnt;
    int srow;
    if (MODE == 0) srow = gm;
    else if (MODE == 1) srow = v ? perm[off + gm] : 0;
    else srow = off + gm;
    lr[c] = r; apc[c] = pc; arow[c] = srow; avld[c] = v;
  }
  int blr[BCH], bpc[BCH];
  for (int c = 0; c < BCH; ++c) {
    int chunk = tid + c * 256;
    blr[c] = chunk >> 2; bpc[c] = chunk & 3;
  }

  const f32x4 z4 = {0.f, 0.f, 0.f, 0.f};
  f32x4 acc[TM][TN];
  for (int r = 0; r < TM; ++r)
    for (int c = 0; c < TN; ++c) acc[r][c] = z4;

  for (int k0 = 0; k0 < K; k0 += 32) {
    __syncthreads();
    uint4 zz = {0u, 0u, 0u, 0u};
    for (int c = 0; c < ACH; ++c) {
      uint4 d = avld[c] ? *(const uint4*)(A + (size_t)arow[c] * K + k0 + apc[c] * 8) : zz;
      *(uint4*)(Ald + lr[c] * 32 + ((apc[c] + lr[c]) & 3) * 8) = d;
    }
    for (int c = 0; c < BCH; ++c) {
      *(uint4*)(Bld + blr[c] * 32 + ((bpc[c] + blr[c]) & 3) * 8) =
          *(const uint4*)(B0 + (size_t)(n0 + blr[c]) * K + k0 + bpc[c] * 8);
    }
    __syncthreads();
    bf16x8 af[TM], bfr[TN];
    for (int r = 0; r < TM; ++r) {
      int row = wr + r * 16 + col;
      af[r] = *(const bf16x8*)(Ald + row * 32 + (((quad + row) & 3) << 3));
    }
    for (int c = 0; c < TN; ++c) {
      int row = wc + c * 16 + col;
      bfr[c] = *(const bf16x8*)(Bld + row * 32 + (((quad + row) & 3) << 3));
    }
    for (int r = 0; r < TM; ++r)
      for (int c = 0; c < TN; ++c)
        acc[r][c] = __builtin_amdgcn_mfma_f32_16x16x32_bf16(af[r], bfr[c], acc[r][c], 0, 0, 0);
  }

  for (int r = 0; r < TM; ++r)
    for (int c = 0; c < TN; ++c) {
      int mloc = wr + r * 16 + quad * 4;
      int n = n0 + wc + c * 16 + col;
      for (int i = 0; i < 4; ++i) {
        int gm = m0 + mloc + i;
        float av = acc[r][c][i];
        if (MODE == 0) {
          float bias = (n < 768) ? biasA[n] : (n < 1536) ? biasB[n - 768] : biasC[n - 1536];
          outB[(size_t)gm * N + n] = (bf16_t)(av + bias);
        } else if (MODE == 1) {
          if (gm < cnt) {
            float vv = av + biasA[(size_t)e * biasStride + n];
            vv = 0.5f * vv * (1.f + erff(vv * 0.70710678118654752f));
            outB[(size_t)(off + gm) * N + n] = (bf16_t)vv;
          }
        } else {
          if (gm < cnt) {
            int tok = perm[off + gm];
            size_t o = (size_t)tok * N + n;
            outF[o] = xin[o] + av + biasA[(size_t)e * biasStride + n];
          }
        }
      }
    }
}

// ---------------------------------------------------------------- attention (block = (qtile, b*h))
__global__ __launch_bounds__(256) void attn_k(const bf16_t* __restrict__ qkv,
                                              const int* __restrict__ np,
                                              float* __restrict__ x) {
  __shared__ bf16_t Kld[256 * 64];   // later reused as P (4 waves x 16 x 256)
  __shared__ bf16_t Vld[256 * 64];
  int tid = threadIdx.x;
  int qt = blockIdx.x;
  int b = blockIdx.y / NHc, h = blockIdx.y % NHc;
  // stage K and V rows (row = tid) with 16B-chunk rotation swizzle on K
  {
    const uint4* ks = (const uint4*)(qkv + ((size_t)(b * 256 + tid)) * 2304 + 768 + h * 64);
    const uint4* vs = (const uint4*)(qkv + ((size_t)(b * 256 + tid)) * 2304 + 1536 + h * 64);
    uint4* kd = (uint4*)(Kld + tid * 64);
    uint4* vd = (uint4*)(Vld + tid * 64);
    for (int j = 0; j < 8; ++j) {
      kd[(j + tid) & 7] = ks[j];
      vd[j] = vs[j];
    }
  }
  int lane = tid & 63, w = tid >> 6;
  int quad = lane >> 4, col = lane & 15;
  float madd[16];
  for (int nt = 0; nt < 16; ++nt)
    madd[nt] = (np[b * 256 + nt * 16 + col] != 0) ? 0.f : -10000.f;
  int qrow = qt * 64 + w * 16 + col;
  const bf16_t* qb = qkv + ((size_t)(b * 256 + qrow)) * 2304 + h * 64;
  bf16x8 qf0 = *(const bf16x8*)(qb + quad * 8);
  bf16x8 qf1 = *(const bf16x8*)(qb + 32 + quad * 8);
  __syncthreads();

  const f32x4 z4 = {0.f, 0.f, 0.f, 0.f};
  f32x4 sc[16];
  for (int nt = 0; nt < 16; ++nt) {
    int row = nt * 16 + col;
    bf16x8 k0 = *(const bf16x8*)(Kld + row * 64 + (((0 + quad + row) & 7) << 3));
    bf16x8 k1 = *(const bf16x8*)(Kld + row * 64 + (((4 + quad + row) & 7) << 3));
    f32x4 z = z4;
    z = __builtin_amdgcn_mfma_f32_16x16x32_bf16(qf0, k0, z, 0, 0, 0);
    z = __builtin_amdgcn_mfma_f32_16x16x32_bf16(qf1, k1, z, 0, 0, 0);
    sc[nt] = z;
  }
  for (int nt = 0; nt < 16; ++nt) {
    float a = madd[nt];
    sc[nt][0] += a; sc[nt][1] += a; sc[nt][2] += a; sc[nt][3] += a;
  }
  float pm[4], rl[4];
  for (int i = 0; i < 4; ++i) {
    float m = -1e30f;
    for (int nt = 0; nt < 16; ++nt) m = fmaxf(m, sc[nt][i]);
    for (int o = 1; o < 16; o <<= 1) m = fmaxf(m, __shfl_xor(m, o));
    float ssum = 0.f;
    for (int nt = 0; nt < 16; ++nt) ssum += __expf(sc[nt][i] - m);
    for (int o = 1; o < 16; o <<= 1) ssum += __shfl_xor(ssum, o);
    pm[i] = m;
    rl[i] = 1.f / ssum;
  }
  __syncthreads();  // everyone done reading Kld
  bf16_t* Pb = Kld + w * 4096;  // this wave's 16 x 256 prob tile
  for (int nt = 0; nt < 16; ++nt)
    for (int i = 0; i < 4; ++i) {
      int prow = quad * 4 + i;
      int key = nt * 16 + col;
      Pb[prow * 256 + (((key >> 3) + prow) & 31) * 8 + (key & 7)] =
          (bf16_t)__expf(sc[nt][i] - pm[i]);
    }
  __syncthreads();
  f32x4 oacc[4];
  for (int i = 0; i < 4; ++i) oacc[i] = z4;
  for (int kk2 = 0; kk2 < 8; ++kk2) {
    bf16x8 pa = *(const bf16x8*)(Pb + col * 256 + (((kk2 * 4 + quad + col) & 31) << 3));
    for (int nt2 = 0; nt2 < 4; ++nt2) {
      bf16x8 bv8;
      for (int j = 0; j < 8; ++j)
        bv8[j] = Vld[(kk2 * 32 + quad * 8 + j) * 64 + nt2 * 16 + col];
      oacc[nt2] = __builtin_amdgcn_mfma_f32_16x16x32_bf16(pa, bv8, oacc[nt2], 0, 0, 0);
    }
  }
  for (int nt2 = 0; nt2 < 4; ++nt2)
    for (int i = 0; i < 4; ++i) {
      size_t o = ((size_t)(b * 256 + qt * 64 + w * 16 + quad * 4 + i)) * Hc + h * 64 + nt2 * 16 + col;
      x[o] += oacc[nt2][i] * rl[i];
    }
}

// ---------------------------------------------------------------- permute via note_pos
__global__ __launch_bounds__(256) void permute_k(const float* __restrict__ xf,
                                                 const int* __restrict__ np,
                                                 float* __restrict__ dst) {
  int i = blockIdx.x * 256 + threadIdx.x;  // over T*192 float4s
  int t = i / 192, d = i - t * 192;
  int idx = np[t];
  float4 v;
  if (idx != 0) v = ((const float4*)xf)[(size_t)(idx - 1) * 192 + d];
  else { v.x = v.y = v.z = v.w = 0.f; }
  ((float4*)dst)[i] = v;
}

// ---------------------------------------------------------------- host
extern "C" void kernel_launch(void* const* d_in, const int* in_sizes, int n_in,
                              void* d_out, int out_size, void* d_ws, size_t ws_size,
                              hipStream_t stream) {
  const float* x_in = (const float*)d_in[0];
  const int* note_pos = (const int*)d_in[1];
  const int* ntp = (const int*)d_in[2];
  const float* Wq = (const float*)d_in[3];
  const float* bq = (const float*)d_in[4];
  const float* Wk = (const float*)d_in[5];
  const float* bk = (const float*)d_in[6];
  const float* Wv = (const float*)d_in[7];
  const float* bv = (const float*)d_in[8];
  const float* ln1w = (const float*)d_in[9];
  const float* ln1b = (const float*)d_in[10];
  const float* ln2w = (const float*)d_in[11];
  const float* ln2b = (const float*)d_in[12];
  const float* W1 = (const float*)d_in[13];
  const float* b1 = (const float*)d_in[14];
  const float* W2 = (const float*)d_in[15];
  const float* b2 = (const float*)d_in[16];
  float* out = (float*)d_out;

  char* p = (char*)d_ws;
  auto carve = [&](size_t bytes) -> char* {
    char* r = p;
    p += (bytes + 255) & ~(size_t)255;
    return r;
  };
  float* x0 = (float*)carve((size_t)Tc * Hc * 4);
  float* x1 = (float*)carve((size_t)Tc * Hc * 4);
  bf16_t* h16 = (bf16_t*)carve((size_t)Tc * Hc * 2);
  bf16_t* big = (bf16_t*)carve((size_t)Tc * FFc * 2);  // union: qkv16 / act1
  bf16_t* qkv16 = big;
  bf16_t* act1 = big;
  bf16_t* wqkvt = (bf16_t*)carve((size_t)2304 * 768 * 2);
  bf16_t* w1t = (bf16_t*)carve((size_t)NEc * FFc * Hc * 2);
  bf16_t* w2t = (bf16_t*)carve((size_t)NEc * Hc * FFc * 2);
  int* perm = (int*)carve(Tc * 4);
  int* offs = (int*)carve(64);

  route_k<<<1, 256, 0, stream>>>(ntp, perm, offs);
  pe_add<<<Tc * Hc / 2 / 256, 256, 0, stream>>>(x_in, x0);

  for (int l = 0; l < Lc; ++l) {
    tconv<<<dim3(12, 12, 3), 256, 0, stream>>>(Wq + (size_t)l * Hc * Hc, Wk + (size_t)l * Hc * Hc,
                                               Wv + (size_t)l * Hc * Hc, 0L, wqkvt, (long)Hc * Hc,
                                               Hc, Hc);
    tconv<<<dim3(48, 12, 4), 256, 0, stream>>>(W1 + (size_t)l * NEc * Hc * FFc, nullptr, nullptr,
                                               (long)Hc * FFc, w1t, (long)FFc * Hc, Hc, FFc);
    tconv<<<dim3(12, 48, 4), 256, 0, stream>>>(W2 + (size_t)l * NEc * FFc * Hc, nullptr, nullptr,
                                               (long)FFc * Hc, w2t, (long)Hc * FFc, FFc, Hc);
    ln_k<<<Tc / 4, 256, 0, stream>>>(x0, ln1w + l * Hc, ln1b + l * Hc, h16);
    gemm_bt<128, 128, 0><<<dim3(2304 / 128, Tc / 128, 1), 256, 0, stream>>>(
        h16, wqkvt, Tc, Hc, 2304, 0L, 0L, perm, offs, bq + l * Hc, bk + l * Hc, bv + l * Hc,
        nullptr, nullptr, qkv16);
    attn_k<<<dim3(4, Bc * NHc), 256, 0, stream>>>(qkv16, note_pos, x0);
    ln_k<<<Tc / 4, 256, 0, stream>>>(x0, ln2w + l * Hc, ln2b + l * Hc, h16);
    gemm_bt<128, 128, 1><<<dim3(FFc / 128, Tc / 128, NEc), 256, 0, stream>>>(
        h16, w1t, Tc, Hc, FFc, (long)FFc * Hc, (long)FFc, perm, offs,
        b1 + (size_t)l * NEc * FFc, nullptr, nullptr, nullptr, nullptr, act1);
    gemm_bt<64, 64, 2><<<dim3(Hc / 64, Tc / 64, NEc), 256, 0, stream>>>(
        act1, w2t, Tc, FFc, Hc, (long)Hc * FFc, (long)Hc, perm, offs,
        b2 + (size_t)l * NEc * Hc, nullptr, nullptr, x0, x1, nullptr);
    permute_k<<<Tc * 192 / 256, 256, 0, stream>>>(x1, note_pos, (l == Lc - 1) ? out : x0);
  }
}